// Round 1
// baseline (939.713 us; speedup 1.0000x reference)
//
#include <hip/hip_runtime.h>
#include <math.h>

// DecoderCategorical: probs = softmax-ish([exp(beta[:-1]@z), 1]) -> one-hot(argmax)
// Z: (T, 64) fp32, beta: (32, 64) fp32 (row 31 unused), out: (T, 32) fp32 one-hot.
// Memory-bound: 768 MB traffic -> ~122 us floor at 6.3 TB/s.

constexpr int DZ = 64;
constexpr int DC = 32;
constexpr int NC = 31;          // active categories (beta[:-1])
constexpr int BLOCK = 256;      // threads per block = rows per block
constexpr int CHUNK = 32;       // cols staged per pass (2 passes over DZ)
constexpr int F4_PER_ROW = CHUNK / 4;  // 8 float4 chunks per row-chunk

__global__ __launch_bounds__(BLOCK, 4) void decoder_cat_kernel(
    const float* __restrict__ Z, const float* __restrict__ beta,
    float* __restrict__ out, int T)
{
    // XOR-swizzled tile: row r, float4-slot s holds chunk (s ^ (r&7)).
    // 32 KB -> 4-5 blocks/CU. Swizzle spreads banks w/o padding so both the
    // coalesced staging writes and per-row b128 reads avoid worst-case conflicts.
    __shared__ float zt[BLOCK * CHUNK];

    const int tid  = threadIdx.x;
    const int row0 = blockIdx.x * BLOCK;

    float acc[NC];
#pragma unroll
    for (int c = 0; c < NC; ++c) acc[c] = 0.0f;

#pragma unroll
    for (int h = 0; h < DZ / CHUNK; ++h) {
        __syncthreads();  // protect zt from previous pass's readers
        // Stage BLOCK rows x CHUNK cols, fully coalesced float4 loads.
#pragma unroll
        for (int k = 0; k < F4_PER_ROW; ++k) {
            int fi = tid + BLOCK * k;       // 0..2047 flat float4 index
            int r  = fi >> 3;               // row within tile
            int c4 = fi & 7;                // float4 chunk within row
            float4 v = make_float4(0.f, 0.f, 0.f, 0.f);
            int grow = row0 + r;
            if (grow < T)
                v = *(const float4*)(Z + (size_t)grow * DZ + h * CHUNK + c4 * 4);
            int sc4 = c4 ^ (r & 7);         // xor swizzle
            *(float4*)(zt + r * CHUNK + sc4 * 4) = v;
        }
        __syncthreads();

        // Each thread: its own row from LDS (b128), beta via uniform scalar
        // loads (s_load_dwordx4 — constant offsets after unroll, kernarg base).
#pragma unroll
        for (int d4 = 0; d4 < F4_PER_ROW; ++d4) {
            int sd4 = d4 ^ (tid & 7);
            float4 z4 = *(const float4*)(zt + tid * CHUNK + sd4 * 4);
#pragma unroll
            for (int c = 0; c < NC; ++c) {
                const float* b = beta + c * DZ + h * CHUNK + d4 * 4;
                // strictly sequential d-order accumulation (matches ref closely)
                acc[c] = fmaf(b[3], z4.w,
                         fmaf(b[2], z4.z,
                         fmaf(b[1], z4.y,
                         fmaf(b[0], z4.x, acc[c]))));
            }
        }
    }

    // Mirror reference: e = exp(logits); norm = 1 + sum(e);
    // probs = [e/norm, 1/norm]; argmax first-max-wins.
    float s = 1.0f;
#pragma unroll
    for (int c = 0; c < NC; ++c) s += expf(acc[c]);

    float best = -1.0f;
    int   bidx = 0;
#pragma unroll
    for (int c = 0; c < NC; ++c) {
        float p = expf(acc[c]) / s;   // IEEE divide, CSE'd expf
        if (p > best) { best = p; bidx = c; }
    }
    if (1.0f / s > best) bidx = NC;   // last category: prob 1/norm

    // Coalesced one-hot stores: redistribute argmax indices across the wave
    // via shuffle so each store inst writes 1 KB contiguous.
    const int lane  = tid & 63;
    const int wrow0 = row0 + (tid & ~63);   // first row owned by this wave
#pragma unroll
    for (int k = 0; k < 8; ++k) {
        int cid = lane + 64 * k;            // 0..511: 64 rows x 8 float4 chunks
        int r   = cid >> 3;
        int c4  = cid & 7;
        int widx = __shfl(bidx, r, 64);
        int grow = wrow0 + r;
        if (grow < T) {
            float4 v;
            v.x = (c4 * 4 + 0 == widx) ? 1.0f : 0.0f;
            v.y = (c4 * 4 + 1 == widx) ? 1.0f : 0.0f;
            v.z = (c4 * 4 + 2 == widx) ? 1.0f : 0.0f;
            v.w = (c4 * 4 + 3 == widx) ? 1.0f : 0.0f;
            *(float4*)(out + (size_t)grow * DC + c4 * 4) = v;
        }
    }
}

extern "C" void kernel_launch(void* const* d_in, const int* in_sizes, int n_in,
                              void* d_out, int out_size, void* d_ws, size_t ws_size,
                              hipStream_t stream)
{
    const float* Z    = (const float*)d_in[0];
    const float* beta = (const float*)d_in[1];
    float* out        = (float*)d_out;
    const int T = in_sizes[0] / DZ;           // 2,000,000
    const int grid = (T + BLOCK - 1) / BLOCK; // 7813
    hipLaunchKernelGGL(decoder_cat_kernel, dim3(grid), dim3(BLOCK), 0, stream,
                       Z, beta, out, T);
}

// Round 2
// 741.918 us; speedup vs baseline: 1.2666x; 1.2666x over previous
//
#include <hip/hip_runtime.h>
#include <math.h>

// DecoderCategorical: probs = [exp(beta[:-1]@z), 1] / (1+sum) -> one-hot(argmax)
// Z: (T, 64) fp32, beta: (32, 64) fp32 (row 31 unused), out: (T, 32) fp32 one-hot.
// v2: no LDS / no barriers. Z has zero cross-thread reuse, so each thread
// streams its own 256 B row via 4x global_load_dwordx4 (16 KB contiguous per
// wave -> full 128 B line utilization, same DRAM traffic as the staged
// version, none of the barrier-drain serialization). beta accesses are
// thread-uniform -> scalar s_load path, SGPR operand in v_fmac.

constexpr int DZ = 64;
constexpr int DC = 32;
constexpr int NC = 31;          // active categories (beta[:-1])
constexpr int BLOCK = 256;

__global__ __launch_bounds__(BLOCK) void decoder_cat_kernel(
    const float* __restrict__ Z, const float* __restrict__ beta,
    float* __restrict__ out, int T)
{
    const int tid  = threadIdx.x;
    const int row  = blockIdx.x * BLOCK + tid;
    const bool live = (row < T);

    // Stream own row: 16 float4 = 64 floats in VGPRs.
    float4 z[16];
    if (live) {
        const float4* zp = (const float4*)(Z + (size_t)row * DZ);
#pragma unroll
        for (int i = 0; i < 16; ++i) z[i] = zp[i];
    } else {
#pragma unroll
        for (int i = 0; i < 16; ++i) z[i] = make_float4(0.f, 0.f, 0.f, 0.f);
    }

    float acc[NC];
#pragma unroll
    for (int c = 0; c < NC; ++c) acc[c] = 0.0f;

    // Fully unrolled 31x64 MAC. beta index is thread-uniform (no tid) ->
    // compiler emits s_load; v_fmac_f32 acc, s_beta, v_z (1 SGPR operand ok).
    // Sequential-d fmaf order per category matches the passing v1 exactly.
#pragma unroll
    for (int d4 = 0; d4 < 16; ++d4) {
        const float4 z4 = z[d4];
#pragma unroll
        for (int c = 0; c < NC; ++c) {
            const float* b = beta + c * DZ + d4 * 4;
            acc[c] = fmaf(b[3], z4.w,
                     fmaf(b[2], z4.z,
                     fmaf(b[1], z4.y,
                     fmaf(b[0], z4.x, acc[c]))));
        }
    }

    // e = exp(logits) once (explicit CSE); norm = 1 + sum(e).
    float s = 1.0f;
#pragma unroll
    for (int c = 0; c < NC; ++c) { acc[c] = expf(acc[c]); s += acc[c]; }

    // probs = [e/norm, 1/norm], first-max-wins argmax. IEEE divides to match
    // the numpy reference's rounding exactly (monotone but tie-creating; the
    // divide must be real to reproduce ref's ties).
    float best = -1.0f;
    int   bidx = 0;
#pragma unroll
    for (int c = 0; c < NC; ++c) {
        float p = acc[c] / s;
        if (p > best) { best = p; bidx = c; }
    }
    if (1.0f / s > best) bidx = NC;

    // Coalesced one-hot stores: redistribute argmax indices across the wave
    // so each store inst writes 1 KB contiguous (64 lanes x float4).
    const int lane  = tid & 63;
    const int wrow0 = blockIdx.x * BLOCK + (tid & ~63);
#pragma unroll
    for (int k = 0; k < 8; ++k) {
        int cid = lane + 64 * k;            // 64 rows x 8 float4 chunks
        int r   = cid >> 3;
        int c4  = cid & 7;
        int widx = __shfl(bidx, r, 64);
        int grow = wrow0 + r;
        if (grow < T) {
            float4 v;
            v.x = (c4 * 4 + 0 == widx) ? 1.0f : 0.0f;
            v.y = (c4 * 4 + 1 == widx) ? 1.0f : 0.0f;
            v.z = (c4 * 4 + 2 == widx) ? 1.0f : 0.0f;
            v.w = (c4 * 4 + 3 == widx) ? 1.0f : 0.0f;
            *(float4*)(out + (size_t)grow * DC + c4 * 4) = v;
        }
    }
}

extern "C" void kernel_launch(void* const* d_in, const int* in_sizes, int n_in,
                              void* d_out, int out_size, void* d_ws, size_t ws_size,
                              hipStream_t stream)
{
    const float* Z    = (const float*)d_in[0];
    const float* beta = (const float*)d_in[1];
    float* out        = (float*)d_out;
    const int T = in_sizes[0] / DZ;           // 2,000,000
    const int grid = (T + BLOCK - 1) / BLOCK; // 7813
    hipLaunchKernelGGL(decoder_cat_kernel, dim3(grid), dim3(BLOCK), 0, stream,
                       Z, beta, out, T);
}